// Round 2
// baseline (178.882 us; speedup 1.0000x reference)
//
#include <hip/hip_runtime.h>
#include <hip/hip_bf16.h>

// ---------------------------------------------------------------------------
// EnhancedUFormerBlock: LN1 -> QKV -> halo attention -> proj(+res) -> LN2
//                       -> MLP(GELU)(+res) -> NCHW output.
// Harness I/O dtype: float32 (per reference). Internals: bf16 MFMA.
// ---------------------------------------------------------------------------

typedef __attribute__((ext_vector_type(8))) short bf16x8;
typedef __attribute__((ext_vector_type(4))) float f32x4;

#define MFMA16(a, b, c) __builtin_amdgcn_mfma_f32_16x16x32_bf16((a), (b), (c), 0, 0, 0)

__device__ __forceinline__ float u2f(unsigned short u) {
  unsigned int x = ((unsigned int)u) << 16;
  return __builtin_bit_cast(float, x);
}
__device__ __forceinline__ unsigned short f2u(float f) {
  unsigned int x = __builtin_bit_cast(unsigned int, f);
  x += 0x7FFFu + ((x >> 16) & 1u);   // RNE
  return (unsigned short)(x >> 16);
}

// ws layout (bytes). Aliases safe per kernel ordering:
//   attnb <- h1 (dead after proj), h2 <- qb (dead after attn),
//   m1 <- kp..vpt (dead after attn). Total ws use ~40.4 MB.
#define O_XHT 0ull                      // f32 residual 1 [16384][128]  8MB
#define O_H1  (8ull << 20)              // bf16 LN1 out   [16384][128]  4MB
#define O_QB  (12ull << 20)             // bf16 Q         [16384][128]  4MB
#define O_XH1 (16ull << 20)             // f32 residual 2 [16384][128]  8MB
#define O_KP  (24ull << 20)             // bf16 K padded  [144*144][128]
#define O_VP  (O_KP + 5308416ull)       // bf16 V padded  [144*144][128]
#define O_VPT (O_VP + 5308416ull)       // bf16 V^T       [128][144*144]
#define O_M1  O_KP                      // bf16 MLP mid   [16384][512] 16MB
#define O_WB  (O_KP + (16ull << 20))    // bf16 weights   ~384KB
#define PADT  20736                     // 144*144 padded tokens

// --------------------- weights f32 -> bf16 (n % 1024 == 0) -----------------
__global__ __launch_bounds__(256) void cvt_kernel(
    const float* __restrict__ src, unsigned short* __restrict__ dst, int n) {
  const int i = (blockIdx.x * 256 + threadIdx.x) * 4;
  if (i < n) {
    const float4 v = *(const float4*)(src + i);
    ushort4 o;
    o.x = f2u(v.x); o.y = f2u(v.y); o.z = f2u(v.z); o.w = f2u(v.w);
    *(ushort4*)(dst + i) = o;
  }
}

// --------------------- LN1 + NCHW->NHWC, wave per token --------------------
__global__ __launch_bounds__(256) void ln1_kernel(
    const float* __restrict__ x,
    const float* __restrict__ lw, const float* __restrict__ lb,
    float* __restrict__ xh_t, unsigned short* __restrict__ h1) {
  const int t = blockIdx.x * 4 + (threadIdx.x >> 6);
  const int l = threadIdx.x & 63;
  const int c0 = l * 2;
  const float v0 = x[(size_t)c0 * 16384 + t];
  const float v1 = x[(size_t)(c0 + 1) * 16384 + t];
  float s = v0 + v1, q = v0 * v0 + v1 * v1;
  for (int d = 1; d < 64; d <<= 1) {
    s += __shfl_xor(s, d);
    q += __shfl_xor(q, d);
  }
  const float mu = s * 0.0078125f;
  const float rs = rsqrtf(q * 0.0078125f - mu * mu + 1e-5f);
  const float y0 = (v0 - mu) * rs * lw[c0] + lb[c0];
  const float y1 = (v1 - mu) * rs * lw[c0 + 1] + lb[c0 + 1];
  *(float2*)(xh_t + (size_t)t * 128 + c0) = float2{v0, v1};
  const unsigned int pk = (unsigned int)f2u(y0) | ((unsigned int)f2u(y1) << 16);
  *(unsigned int*)(h1 + (size_t)t * 128 + c0) = pk;
}

// ------------------------------- LN2 (f32 in) ------------------------------
__global__ __launch_bounds__(256) void ln2_kernel(
    const float* __restrict__ xh1,
    const float* __restrict__ lw, const float* __restrict__ lb,
    unsigned short* __restrict__ h2) {
  const int t = blockIdx.x * 4 + (threadIdx.x >> 6);
  const int l = threadIdx.x & 63;
  const float2 v = *(const float2*)(xh1 + (size_t)t * 128 + l * 2);
  float s = v.x + v.y;
  float q = v.x * v.x + v.y * v.y;
  for (int d = 1; d < 64; d <<= 1) {
    s += __shfl_xor(s, d);
    q += __shfl_xor(q, d);
  }
  const float mu = s * 0.0078125f;
  const float rs = rsqrtf(q * 0.0078125f - mu * mu + 1e-5f);
  const float y0 = (v.x - mu) * rs * lw[2 * l] + lb[2 * l];
  const float y1 = (v.y - mu) * rs * lw[2 * l + 1] + lb[2 * l + 1];
  const unsigned int pk = (unsigned int)f2u(y0) | ((unsigned int)f2u(y1) << 16);
  *(unsigned int*)(h2 + (size_t)t * 128 + l * 2) = pk;
}

// ------------------- V transpose: vp[PADT][128] -> vpt[128][PADT] ----------
__global__ __launch_bounds__(256) void vtrans_kernel(
    const unsigned short* __restrict__ vp, unsigned short* __restrict__ vpt) {
  __shared__ unsigned short t[64][130];
  const int r0 = blockIdx.x * 64;
  const int tid = threadIdx.x;
  {
    const int c = tid & 127, rh = tid >> 7;
    for (int it = 0; it < 32; it++) {
      const int r = it * 2 + rh;
      t[r][c] = vp[(size_t)(r0 + r) * 128 + c];
    }
  }
  __syncthreads();
  {
    const int r = tid & 63, ch = tid >> 6;
    for (int it = 0; it < 32; it++) {
      const int col = it * 4 + ch;
      vpt[(size_t)col * PADT + r0 + r] = t[r][col];
    }
  }
}

// ------------------------------ generic GEMM -------------------------------
// C[M][N] = A[M][K] @ B[N][K]^T + bias. 64x64 tile, 4 waves of 32x32,
// mfma_f32_16x16x32_bf16, direct global fragment loads (L2-resident data).
enum { EPI_QKV = 0, EPI_PROJ = 1, EPI_GELU = 2, EPI_FC2 = 3 };

template <int EPI, int K>
__global__ __launch_bounds__(256) void gemm_kernel(
    const unsigned short* __restrict__ A,
    const unsigned short* __restrict__ B,
    const float* __restrict__ bias,
    void* __restrict__ o0, void* __restrict__ o1, void* __restrict__ o2,
    const void* __restrict__ aux) {
  const int tid = threadIdx.x;
  const int w = tid >> 6, l = tid & 63;
  const int lr = l & 15, lg = l >> 4;
  const int m0 = blockIdx.x * 64 + (w >> 1) * 32;
  const int n0 = blockIdx.y * 64 + (w & 1) * 32;
  f32x4 acc[2][2] = {};
  const unsigned short* Ar0 = A + (size_t)(m0 + lr) * K + lg * 8;
  const unsigned short* Ar1 = Ar0 + 16 * K;
  const unsigned short* Br0 = B + (size_t)(n0 + lr) * K + lg * 8;
  const unsigned short* Br1 = Br0 + 16 * K;
  for (int k = 0; k < K; k += 32) {
    bf16x8 a0 = *(const bf16x8*)(Ar0 + k);
    bf16x8 a1 = *(const bf16x8*)(Ar1 + k);
    bf16x8 b0 = *(const bf16x8*)(Br0 + k);
    bf16x8 b1 = *(const bf16x8*)(Br1 + k);
    acc[0][0] = MFMA16(a0, b0, acc[0][0]);
    acc[0][1] = MFMA16(a0, b1, acc[0][1]);
    acc[1][0] = MFMA16(a1, b0, acc[1][0]);
    acc[1][1] = MFMA16(a1, b1, acc[1][1]);
  }
#pragma unroll
  for (int j = 0; j < 2; j++) {
    const int jj = n0 + j * 16 + lr;
    const float bv = bias[jj];
#pragma unroll
    for (int i = 0; i < 2; i++) {
#pragma unroll
      for (int r = 0; r < 4; r++) {
        const int ii = m0 + i * 16 + lg * 4 + r;
        float v = acc[i][j][r] + bv;
        if constexpr (EPI == EPI_QKV) {
          const int gh = ii >> 7, gw = ii & 127;
          const size_t prow = (size_t)(gh + 8) * 144 + (gw + 8);
          if (jj < 128)
            ((unsigned short*)o0)[(size_t)ii * 128 + jj] = f2u(v);
          else if (jj < 256)
            ((unsigned short*)o1)[prow * 128 + (jj - 128)] = f2u(v);
          else
            ((unsigned short*)o2)[prow * 128 + (jj - 256)] = f2u(v);
        } else if constexpr (EPI == EPI_PROJ) {
          v += ((const float*)aux)[(size_t)ii * 128 + jj];
          ((float*)o0)[(size_t)ii * 128 + jj] = v;
        } else if constexpr (EPI == EPI_GELU) {
          const float g = 0.5f * v * (1.0f + erff(v * 0.70710678118f));
          ((unsigned short*)o0)[(size_t)ii * 512 + jj] = f2u(g);
        } else {  // EPI_FC2: +residual, NCHW f32 store
          v += ((const float*)aux)[(size_t)ii * 128 + jj];
          ((float*)o0)[(size_t)jj * 16384 + ii] = v;
        }
      }
    }
  }
}

// ------------------------------ halo attention -----------------------------
// Block = (window, head); 4 waves, each owns 64 queries (4 q-tiles of 16).
// Swapped QK^T: D[key][q] = mfma(K_frag, Q^T_frag). Q pre-scaled by
// 0.25*log2(e); p = exp2(s) == exp(qk/4), no max subtraction needed
// (|s| <~ 12 in f32, safe) -> matches reference softmax incl. zero-padded
// OOB keys (score 0 -> weight 1 in the denominator, value 0).
__global__ __launch_bounds__(256) void attn_kernel(
    const unsigned short* __restrict__ qb,
    const unsigned short* __restrict__ kp,
    const unsigned short* __restrict__ vpt,
    unsigned short* __restrict__ attnb) {
  const int head = blockIdx.x & 7;
  const int win = blockIdx.x >> 3;
  const int wy = win >> 3, wx = win & 7;
  const int tid = threadIdx.x;
  const int wv = tid >> 6;
  const int l = tid & 63;
  const int lr = l & 15, lg = l >> 4;
  const float QS = 0.25f * 1.4426950408889634f;

  // Q^T B-fragments (col q = lr, k = hd = lg*8+e, real only hd<16)
  bf16x8 qf[4];
#pragma unroll
  for (int qt = 0; qt < 4; qt++) {
    bf16x8 t = {};
    if (lg < 2) {
      const int qi = wv * 64 + qt * 16 + lr;
      const int gh = wy * 16 + (qi >> 4), gw = wx * 16 + (qi & 15);
      t = *(const bf16x8*)(qb + ((size_t)(gh * 128 + gw)) * 128 + head * 16 + lg * 8);
#pragma unroll
      for (int e = 0; e < 8; e++)
        t[e] = (short)f2u(u2f((unsigned short)t[e]) * QS);
    }
    qf[qt] = t;
  }

  f32x4 acc[4] = {};
  float lsum[4] = {};

  for (int kr = 0; kr < 32; kr++) {      // one halo row = 32 keys
    const size_t pbase = (size_t)(wy * 16 + kr) * 144 + wx * 16;
    bf16x8 kf0 = {}, kf1 = {};
    if (lg < 2) {
      kf0 = *(const bf16x8*)(kp + (pbase + lr) * 128 + head * 16 + lg * 8);
      kf1 = *(const bf16x8*)(kp + (pbase + 16 + lr) * 128 + head * 16 + lg * 8);
    }
    const bf16x8 vf = *(const bf16x8*)(vpt + (size_t)(head * 16 + lr) * PADT + pbase + lg * 8);
#pragma unroll
    for (int qt = 0; qt < 4; qt++) {
      f32x4 s0 = {}, s1 = {};
      s0 = MFMA16(kf0, qf[qt], s0);      // D[key 0..15][q=lr]
      s1 = MFMA16(kf1, qf[qt], s1);      // D[key 16..31][q=lr]
      float p0[4], p1[4];
      float ls = 0.f;
#pragma unroll
      for (int r = 0; r < 4; r++) {
        p0[r] = exp2f(s0[r]);
        p1[r] = exp2f(s1[r]);
        ls += p0[r] + p1[r];
      }
      lsum[qt] += ls;
      // redistribute P into the PV A-fragment (row q = lr, k = key = lg*8+j)
      bf16x8 pa;
#pragma unroll
      for (int jj = 0; jj < 8; jj++) {
        const int src = (((lg & 1) * 2 + (jj >> 2)) << 4) | lr;
        const float w0 = __shfl(p0[jj & 3], src);
        const float w1 = __shfl(p1[jj & 3], src);
        pa[jj] = (short)f2u(lg >= 2 ? w1 : w0);
      }
      acc[qt] = MFMA16(pa, vf, acc[qt]);
    }
  }

#pragma unroll
  for (int qt = 0; qt < 4; qt++) {
    float lt = lsum[qt];
    lt += __shfl_xor(lt, 16);
    lt += __shfl_xor(lt, 32);
    const float inv = 1.0f / lt;         // denominator for q = lr
#pragma unroll
    for (int r = 0; r < 4; r++) {
      const float invq = __shfl(inv, lg * 4 + r);
      const int qi = wv * 64 + qt * 16 + lg * 4 + r;
      const int gh = wy * 16 + (qi >> 4), gw = wx * 16 + (qi & 15);
      attnb[((size_t)(gh * 128 + gw)) * 128 + head * 16 + lr] = f2u(acc[qt][r] * invq);
    }
  }
}

// ------------------------------- launcher ----------------------------------
extern "C" void kernel_launch(void* const* d_in, const int* in_sizes, int n_in,
                              void* d_out, int out_size, void* d_ws, size_t ws_size,
                              hipStream_t stream) {
  const float* x      = (const float*)d_in[0];
  const float* ln1w   = (const float*)d_in[1];
  const float* ln1b   = (const float*)d_in[2];
  const float* qkv_w  = (const float*)d_in[3];
  const float* qkv_b  = (const float*)d_in[4];
  const float* proj_w = (const float*)d_in[5];
  const float* proj_b = (const float*)d_in[6];
  const float* ln2w   = (const float*)d_in[7];
  const float* ln2b   = (const float*)d_in[8];
  const float* fc1_w  = (const float*)d_in[9];
  const float* fc1_b  = (const float*)d_in[10];
  const float* fc2_w  = (const float*)d_in[11];
  const float* fc2_b  = (const float*)d_in[12];

  char* ws = (char*)d_ws;
  float*          xh_t = (float*)(ws + O_XHT);
  unsigned short* h1   = (unsigned short*)(ws + O_H1);
  unsigned short* qb   = (unsigned short*)(ws + O_QB);
  float*          xh1  = (float*)(ws + O_XH1);
  unsigned short* kp   = (unsigned short*)(ws + O_KP);
  unsigned short* vp   = (unsigned short*)(ws + O_VP);
  unsigned short* vpt  = (unsigned short*)(ws + O_VPT);
  unsigned short* m1   = (unsigned short*)(ws + O_M1);
  unsigned short* wb   = (unsigned short*)(ws + O_WB);
  unsigned short* attnb = h1;   // h1 dead after QKV+attn is wrong order? no: attn writes after QKV read
  unsigned short* h2    = qb;   // qb dead after attention
  float* outp = (float*)d_out;

  unsigned short* qkv_wb = wb;                 // 49152
  unsigned short* proj_wb = wb + 49152;        // 16384
  unsigned short* fc1_wb  = wb + 65536;        // 65536
  unsigned short* fc2_wb  = wb + 131072;       // 65536

  // convert weights to bf16 (every call; deterministic)
  cvt_kernel<<<48, 256, 0, stream>>>(qkv_w,  qkv_wb, 49152);
  cvt_kernel<<<16, 256, 0, stream>>>(proj_w, proj_wb, 16384);
  cvt_kernel<<<64, 256, 0, stream>>>(fc1_w,  fc1_wb, 65536);
  cvt_kernel<<<64, 256, 0, stream>>>(fc2_w,  fc2_wb, 65536);

  // zero halo pads (interior overwritten by QKV epilogue every call)
  hipMemsetAsync(kp, 0, 5308416, stream);
  hipMemsetAsync(vp, 0, 5308416, stream);

  ln1_kernel<<<4096, 256, 0, stream>>>(x, ln1w, ln1b, xh_t, h1);
  gemm_kernel<EPI_QKV, 128><<<dim3(256, 6), 256, 0, stream>>>(
      h1, qkv_wb, qkv_b, qb, kp, vp, nullptr);
  vtrans_kernel<<<324, 256, 0, stream>>>(vp, vpt);
  attn_kernel<<<512, 256, 0, stream>>>(qb, kp, vpt, attnb);
  gemm_kernel<EPI_PROJ, 128><<<dim3(256, 2), 256, 0, stream>>>(
      attnb, proj_wb, proj_b, xh1, nullptr, nullptr, xh_t);
  ln2_kernel<<<4096, 256, 0, stream>>>(xh1, ln2w, ln2b, h2);
  gemm_kernel<EPI_GELU, 128><<<dim3(256, 8), 256, 0, stream>>>(
      h2, fc1_wb, fc1_b, m1, nullptr, nullptr, nullptr);
  gemm_kernel<EPI_FC2, 512><<<dim3(256, 2), 256, 0, stream>>>(
      m1, fc2_wb, fc2_b, outp, nullptr, nullptr, xh1);
}

// Round 3
// 137.154 us; speedup vs baseline: 1.3042x; 1.3042x over previous
//
#include <hip/hip_runtime.h>
#include <hip/hip_bf16.h>

// ---------------------------------------------------------------------------
// EnhancedUFormerBlock: LN1 -> QKV -> halo attention -> proj(+res) -> LN2
//                       -> MLP(GELU)(+res) -> NCHW output.
// Harness I/O dtype: float32 (per reference). Internals: bf16 MFMA.
// ---------------------------------------------------------------------------

typedef __attribute__((ext_vector_type(8))) short bf16x8;
typedef __attribute__((ext_vector_type(4))) float f32x4;
typedef __attribute__((ext_vector_type(4))) unsigned int u32x4;

#define MFMA16(a, b, c) __builtin_amdgcn_mfma_f32_16x16x32_bf16((a), (b), (c), 0, 0, 0)

__device__ __forceinline__ float u2f(unsigned short u) {
  unsigned int x = ((unsigned int)u) << 16;
  return __builtin_bit_cast(float, x);
}
__device__ __forceinline__ unsigned short f2u(float f) {
  unsigned int x = __builtin_bit_cast(unsigned int, f);
  x += 0x7FFFu + ((x >> 16) & 1u);   // RNE
  return (unsigned short)(x >> 16);
}
// D[15:0]=bf16(lo), D[31:16]=bf16(hi) -- single instruction, RNE.
__device__ __forceinline__ unsigned int cvt_pk_bf16(float lo, float hi) {
  unsigned int r;
  asm("v_cvt_pk_bf16_f32 %0, %1, %2" : "=v"(r) : "v"(lo), "v"(hi));
  return r;
}

// ws layout (bytes). Aliases safe per kernel ordering:
//   attnb <- h1 (dead after attn input read), h2 <- qb (dead after attn),
//   m1 <- kp..vpt (dead after attn). Total ws use ~40.4 MB.
#define O_XHT 0ull                      // f32 residual 1 [16384][128]  8MB
#define O_H1  (8ull << 20)              // bf16 LN1 out   [16384][128]  4MB
#define O_QB  (12ull << 20)             // bf16 Q         [16384][128]  4MB
#define O_XH1 (16ull << 20)             // f32 residual 2 [16384][128]  8MB
#define O_KP  (24ull << 20)             // bf16 K padded  [144*144][128]
#define O_VP  (O_KP + 5308416ull)       // bf16 V padded  [144*144][128]
#define O_VPT (O_VP + 5308416ull)       // bf16 V^T       [128][144*144]
#define O_M1  O_KP                      // bf16 MLP mid   [16384][512] 16MB
#define O_WB  (O_KP + (16ull << 20))    // bf16 weights   ~384KB
#define PADT  20736                     // 144*144 padded tokens

// ---------------- all weights f32 -> bf16 in one launch --------------------
// dst is the concatenation qkv(49152) | proj(16384) | fc1(65536) | fc2(65536)
__global__ __launch_bounds__(256) void cvtall_kernel(
    const float* __restrict__ a, const float* __restrict__ b,
    const float* __restrict__ c, const float* __restrict__ d,
    unsigned short* __restrict__ dst) {
  const int i = (blockIdx.x * 256 + threadIdx.x) * 4;
  const float* s; int lo;
  if (i < 49152)       { s = a; lo = 0; }
  else if (i < 65536)  { s = b; lo = 49152; }
  else if (i < 131072) { s = c; lo = 65536; }
  else                 { s = d; lo = 131072; }
  const float4 v = *(const float4*)(s + (i - lo));
  ushort4 o;
  o.x = f2u(v.x); o.y = f2u(v.y); o.z = f2u(v.z); o.w = f2u(v.w);
  *(ushort4*)(dst + i) = o;
}

// --------------------- LN1 + NCHW->NHWC, wave per token --------------------
__global__ __launch_bounds__(256) void ln1_kernel(
    const float* __restrict__ x,
    const float* __restrict__ lw, const float* __restrict__ lb,
    float* __restrict__ xh_t, unsigned short* __restrict__ h1) {
  const int t = blockIdx.x * 4 + (threadIdx.x >> 6);
  const int l = threadIdx.x & 63;
  const int c0 = l * 2;
  const float v0 = x[(size_t)c0 * 16384 + t];
  const float v1 = x[(size_t)(c0 + 1) * 16384 + t];
  float s = v0 + v1, q = v0 * v0 + v1 * v1;
  for (int d = 1; d < 64; d <<= 1) {
    s += __shfl_xor(s, d);
    q += __shfl_xor(q, d);
  }
  const float mu = s * 0.0078125f;
  const float rs = rsqrtf(q * 0.0078125f - mu * mu + 1e-5f);
  const float y0 = (v0 - mu) * rs * lw[c0] + lb[c0];
  const float y1 = (v1 - mu) * rs * lw[c0 + 1] + lb[c0 + 1];
  *(float2*)(xh_t + (size_t)t * 128 + c0) = float2{v0, v1};
  *(unsigned int*)(h1 + (size_t)t * 128 + c0) = cvt_pk_bf16(y0, y1);
}

// ------------------------------- LN2 (f32 in) ------------------------------
__global__ __launch_bounds__(256) void ln2_kernel(
    const float* __restrict__ xh1,
    const float* __restrict__ lw, const float* __restrict__ lb,
    unsigned short* __restrict__ h2) {
  const int t = blockIdx.x * 4 + (threadIdx.x >> 6);
  const int l = threadIdx.x & 63;
  const float2 v = *(const float2*)(xh1 + (size_t)t * 128 + l * 2);
  float s = v.x + v.y;
  float q = v.x * v.x + v.y * v.y;
  for (int d = 1; d < 64; d <<= 1) {
    s += __shfl_xor(s, d);
    q += __shfl_xor(q, d);
  }
  const float mu = s * 0.0078125f;
  const float rs = rsqrtf(q * 0.0078125f - mu * mu + 1e-5f);
  const float y0 = (v.x - mu) * rs * lw[2 * l] + lb[2 * l];
  const float y1 = (v.y - mu) * rs * lw[2 * l + 1] + lb[2 * l + 1];
  *(unsigned int*)(h2 + (size_t)t * 128 + l * 2) = cvt_pk_bf16(y0, y1);
}

// ------------------- V transpose: vp[PADT][128] -> vpt[128][PADT] ----------
__global__ __launch_bounds__(256) void vtrans_kernel(
    const unsigned short* __restrict__ vp, unsigned short* __restrict__ vpt) {
  __shared__ unsigned short t[64][130];
  const int r0 = blockIdx.x * 64;
  const int tid = threadIdx.x;
  {
    const int c = tid & 127, rh = tid >> 7;
    for (int it = 0; it < 32; it++) {
      const int r = it * 2 + rh;
      t[r][c] = vp[(size_t)(r0 + r) * 128 + c];
    }
  }
  __syncthreads();
  {
    const int r = tid & 63, ch = tid >> 6;
    for (int it = 0; it < 32; it++) {
      const int col = it * 4 + ch;
      vpt[(size_t)col * PADT + r0 + r] = t[r][col];
    }
  }
}

// ------------------------------ generic GEMM -------------------------------
// C[M][N] = A[M][K] @ B[N][K]^T + bias. 64x64 tile, 4 waves of 32x32,
// mfma_f32_16x16x32_bf16, direct global fragment loads (L2-resident data).
enum { EPI_QKV = 0, EPI_PROJ = 1, EPI_GELU = 2, EPI_FC2 = 3 };

template <int EPI, int K>
__global__ __launch_bounds__(256) void gemm_kernel(
    const unsigned short* __restrict__ A,
    const unsigned short* __restrict__ B,
    const float* __restrict__ bias,
    void* __restrict__ o0, void* __restrict__ o1, void* __restrict__ o2,
    const void* __restrict__ aux) {
  const int tid = threadIdx.x;
  const int w = tid >> 6, l = tid & 63;
  const int lr = l & 15, lg = l >> 4;
  const int mB = blockIdx.x * 64, nB = blockIdx.y * 64;
  const int ml = (w >> 1) * 32, nl2 = (w & 1) * 32;
  const int m0 = mB + ml, n0 = nB + nl2;
  f32x4 acc[2][2] = {};
  const unsigned short* Ar0 = A + (size_t)(m0 + lr) * K + lg * 8;
  const unsigned short* Ar1 = Ar0 + 16 * K;
  const unsigned short* Br0 = B + (size_t)(n0 + lr) * K + lg * 8;
  const unsigned short* Br1 = Br0 + 16 * K;
  for (int k = 0; k < K; k += 32) {
    bf16x8 a0 = *(const bf16x8*)(Ar0 + k);
    bf16x8 a1 = *(const bf16x8*)(Ar1 + k);
    bf16x8 b0 = *(const bf16x8*)(Br0 + k);
    bf16x8 b1 = *(const bf16x8*)(Br1 + k);
    acc[0][0] = MFMA16(a0, b0, acc[0][0]);
    acc[0][1] = MFMA16(a0, b1, acc[0][1]);
    acc[1][0] = MFMA16(a1, b0, acc[1][0]);
    acc[1][1] = MFMA16(a1, b1, acc[1][1]);
  }

  if constexpr (EPI == EPI_FC2) {
    // +residual, then LDS-transpose so the NCHW f32 store is coalesced.
    __shared__ float tb[64][65];
#pragma unroll
    for (int j = 0; j < 2; j++) {
      const int jl = nl2 + j * 16 + lr;
      const float bv = bias[nB + jl];
#pragma unroll
      for (int i = 0; i < 2; i++)
#pragma unroll
        for (int r = 0; r < 4; r++) {
          const int il = ml + i * 16 + lg * 4 + r;
          tb[jl][il] = acc[i][j][r] + bv +
                       ((const float*)aux)[(size_t)(mB + il) * 128 + (nB + jl)];
        }
    }
    __syncthreads();
    const int nrow = tid >> 2, mc = (tid & 3) * 16;
    float* op = (float*)o0 + (size_t)(nB + nrow) * 16384 + mB + mc;
#pragma unroll
    for (int kk = 0; kk < 4; kk++)
      *(float4*)(op + kk * 4) = *(const float4*)&tb[nrow][mc + kk * 4];
  } else {
#pragma unroll
    for (int j = 0; j < 2; j++) {
      const int jj = n0 + j * 16 + lr;
      const float bv = bias[jj];
#pragma unroll
      for (int i = 0; i < 2; i++) {
#pragma unroll
        for (int r = 0; r < 4; r++) {
          const int ii = m0 + i * 16 + lg * 4 + r;
          float v = acc[i][j][r] + bv;
          if constexpr (EPI == EPI_QKV) {
            const int gh = ii >> 7, gw = ii & 127;
            const size_t prow = (size_t)(gh + 8) * 144 + (gw + 8);
            if (jj < 128)
              ((unsigned short*)o0)[(size_t)ii * 128 + jj] = f2u(v);
            else if (jj < 256)
              ((unsigned short*)o1)[prow * 128 + (jj - 128)] = f2u(v);
            else
              ((unsigned short*)o2)[prow * 128 + (jj - 256)] = f2u(v);
          } else if constexpr (EPI == EPI_PROJ) {
            v += ((const float*)aux)[(size_t)ii * 128 + jj];
            ((float*)o0)[(size_t)ii * 128 + jj] = v;
          } else {  // EPI_GELU: tanh-form GELU, one exp2 + rcp
            const float y = 0.7978845608f * (v + 0.044715f * v * v * v);
            const float E = __builtin_amdgcn_exp2f(y * 2.8853900818f);
            const float g = v - v * __builtin_amdgcn_rcpf(E + 1.0f);
            ((unsigned short*)o0)[(size_t)ii * 512 + jj] = f2u(g);
          }
        }
      }
    }
  }
}

// ------------------------------ halo attention -----------------------------
// Block = (window, head, q-half); 4 waves, each wave 32 queries (2 q-tiles).
// Swapped QK^T: D[key][q] = mfma(K_frag, Q^T_frag). Q pre-scaled by
// 0.25*log2(e); p = exp2(s) == exp(qk/4), no max subtraction needed ->
// matches reference softmax incl. zero-padded OOB keys exactly.
// P redistribution (T12-style): cvt_pk packs (p0,p1) per reg, ONE bpermute
// pulls both halves, v_perm_b32 assembles the PV A-fragment word.
__global__ __launch_bounds__(256) void attn_kernel(
    const unsigned short* __restrict__ qb,
    const unsigned short* __restrict__ kp,
    const unsigned short* __restrict__ vpt,
    unsigned short* __restrict__ attnb) {
  const int bid = blockIdx.x;
  const int qh = bid & 1;
  const int head = (bid >> 1) & 7;
  const int win = bid >> 4;
  const int wy = win >> 3, wx = win & 7;
  const int tid = threadIdx.x;
  const int wv = tid >> 6;
  const int l = tid & 63;
  const int lr = l & 15, lg = l >> 4;
  const float QS = 0.25f * 1.4426950408889634f;

  // Q^T B-fragments (col q = lr, k = hd = lg*8+e, real only hd<16)
  bf16x8 qf[2];
#pragma unroll
  for (int qt = 0; qt < 2; qt++) {
    bf16x8 t = {};
    if (lg < 2) {
      const int qi = qh * 128 + wv * 32 + qt * 16 + lr;
      const int gh = wy * 16 + (qi >> 4), gw = wx * 16 + (qi & 15);
      t = *(const bf16x8*)(qb + ((size_t)(gh * 128 + gw)) * 128 + head * 16 + lg * 8);
#pragma unroll
      for (int e = 0; e < 8; e++)
        t[e] = (short)f2u(u2f((unsigned short)t[e]) * QS);
    }
    qf[qt] = t;
  }

  f32x4 acc[2] = {};
  float lsum[2] = {};
  const unsigned int psel = (lg >= 2) ? 0x07060302u : 0x05040100u;
  const int sb0 = ((lg & 1) * 32 + lr) << 2;   // bpermute byte idx, j<4
  const int sb1 = sb0 + (16 << 2);             // j>=4

  for (int kr = 0; kr < 32; kr++) {      // one halo row = 32 keys
    const size_t pbase = (size_t)(wy * 16 + kr) * 144 + wx * 16;
    bf16x8 kf0 = {}, kf1 = {};
    if (lg < 2) {
      kf0 = *(const bf16x8*)(kp + (pbase + lr) * 128 + head * 16 + lg * 8);
      kf1 = *(const bf16x8*)(kp + (pbase + 16 + lr) * 128 + head * 16 + lg * 8);
    }
    const bf16x8 vf = *(const bf16x8*)(vpt + (size_t)(head * 16 + lr) * PADT + pbase + lg * 8);
#pragma unroll
    for (int qt = 0; qt < 2; qt++) {
      f32x4 s0 = {}, s1 = {};
      s0 = MFMA16(kf0, qf[qt], s0);      // D[key 0..15][q=lr]
      s1 = MFMA16(kf1, qf[qt], s1);      // D[key 16..31][q=lr]
      unsigned int pk[4];
      float ls = 0.f;
#pragma unroll
      for (int r = 0; r < 4; r++) {
        const float p0 = __builtin_amdgcn_exp2f(s0[r]);
        const float p1 = __builtin_amdgcn_exp2f(s1[r]);
        ls += p0 + p1;
        pk[r] = cvt_pk_bf16(p0, p1);     // lo=key lg*4+r, hi=key 16+lg*4+r
      }
      lsum[qt] += ls;
      unsigned int vj[8];
#pragma unroll
      for (int j = 0; j < 8; j++)
        vj[j] = (unsigned int)__builtin_amdgcn_ds_bpermute(
            (j < 4) ? sb0 : sb1, (int)pk[j & 3]);
      u32x4 pa;
#pragma unroll
      for (int i2 = 0; i2 < 4; i2++)
        pa[i2] = __builtin_amdgcn_perm(vj[2 * i2 + 1], vj[2 * i2], psel);
      acc[qt] = MFMA16(__builtin_bit_cast(bf16x8, pa), vf, acc[qt]);
    }
  }

#pragma unroll
  for (int qt = 0; qt < 2; qt++) {
    float lt = lsum[qt];
    lt += __shfl_xor(lt, 16);
    lt += __shfl_xor(lt, 32);
    const float inv = 1.0f / lt;         // denominator for q = lr
#pragma unroll
    for (int r = 0; r < 4; r++) {
      const float invq = __shfl(inv, lg * 4 + r);
      const int qi = qh * 128 + wv * 32 + qt * 16 + lg * 4 + r;
      const int gh = wy * 16 + (qi >> 4), gw = wx * 16 + (qi & 15);
      attnb[((size_t)(gh * 128 + gw)) * 128 + head * 16 + lr] = f2u(acc[qt][r] * invq);
    }
  }
}

// ------------------------------- launcher ----------------------------------
extern "C" void kernel_launch(void* const* d_in, const int* in_sizes, int n_in,
                              void* d_out, int out_size, void* d_ws, size_t ws_size,
                              hipStream_t stream) {
  const float* x      = (const float*)d_in[0];
  const float* ln1w   = (const float*)d_in[1];
  const float* ln1b   = (const float*)d_in[2];
  const float* qkv_w  = (const float*)d_in[3];
  const float* qkv_b  = (const float*)d_in[4];
  const float* proj_w = (const float*)d_in[5];
  const float* proj_b = (const float*)d_in[6];
  const float* ln2w   = (const float*)d_in[7];
  const float* ln2b   = (const float*)d_in[8];
  const float* fc1_w  = (const float*)d_in[9];
  const float* fc1_b  = (const float*)d_in[10];
  const float* fc2_w  = (const float*)d_in[11];
  const float* fc2_b  = (const float*)d_in[12];

  char* ws = (char*)d_ws;
  float*          xh_t = (float*)(ws + O_XHT);
  unsigned short* h1   = (unsigned short*)(ws + O_H1);
  unsigned short* qb   = (unsigned short*)(ws + O_QB);
  float*          xh1  = (float*)(ws + O_XH1);
  unsigned short* kp   = (unsigned short*)(ws + O_KP);
  unsigned short* vp   = (unsigned short*)(ws + O_VP);
  unsigned short* vpt  = (unsigned short*)(ws + O_VPT);
  unsigned short* m1   = (unsigned short*)(ws + O_M1);
  unsigned short* wb   = (unsigned short*)(ws + O_WB);
  unsigned short* attnb = h1;   // h1 dead after attn's producer chain read it
  unsigned short* h2    = qb;   // qb dead after attention
  float* outp = (float*)d_out;

  unsigned short* qkv_wb  = wb;            // 49152
  unsigned short* fc1_wb  = wb + 65536;    // 65536
  unsigned short* fc2_wb  = wb + 131072;   // 65536
  unsigned short* proj_wb = wb + 49152;    // 16384

  // weights -> bf16, one launch
  cvtall_kernel<<<192, 256, 0, stream>>>(qkv_w, proj_w, fc1_w, fc2_w, wb);
  // zero halo pads for K and V (contiguous) -- interior rewritten every call
  hipMemsetAsync(kp, 0, 10616832, stream);

  ln1_kernel<<<4096, 256, 0, stream>>>(x, ln1w, ln1b, xh_t, h1);
  gemm_kernel<EPI_QKV, 128><<<dim3(256, 6), 256, 0, stream>>>(
      h1, qkv_wb, qkv_b, qb, kp, vp, nullptr);
  vtrans_kernel<<<324, 256, 0, stream>>>(vp, vpt);
  attn_kernel<<<1024, 256, 0, stream>>>(qb, kp, vpt, attnb);
  gemm_kernel<EPI_PROJ, 128><<<dim3(256, 2), 256, 0, stream>>>(
      attnb, proj_wb, proj_b, xh1, nullptr, nullptr, xh_t);
  ln2_kernel<<<4096, 256, 0, stream>>>(xh1, ln2w, ln2b, h2);
  gemm_kernel<EPI_GELU, 128><<<dim3(256, 8), 256, 0, stream>>>(
      h2, fc1_wb, fc1_b, m1, nullptr, nullptr, nullptr);
  gemm_kernel<EPI_FC2, 512><<<dim3(256, 2), 256, 0, stream>>>(
      m1, fc2_wb, fc2_b, outp, nullptr, nullptr, xh1);
}

// Round 5
// 127.860 us; speedup vs baseline: 1.3990x; 1.0727x over previous
//
#include <hip/hip_runtime.h>
#include <hip/hip_bf16.h>

// ---------------------------------------------------------------------------
// EnhancedUFormerBlock: LN1 -> QKV -> halo attention -> proj(+res)+LN2 ->
//                       MLP(GELU)(+res) -> NCHW output.
// Harness I/O dtype: float32 (per reference). Internals: bf16 MFMA.
// NOTE: only 16x16x32 MFMA fragment layouts are used (validated in rounds
// 2-3); the 32x32x16 A/B layouts proved unreliable in round 4.
// ---------------------------------------------------------------------------

typedef __attribute__((ext_vector_type(8))) short bf16x8;
typedef __attribute__((ext_vector_type(4))) float f32x4;
typedef __attribute__((ext_vector_type(4))) unsigned int u32x4;

#define MFMA16(a, b, c) __builtin_amdgcn_mfma_f32_16x16x32_bf16((a), (b), (c), 0, 0, 0)

__device__ __forceinline__ float u2f(unsigned short u) {
  unsigned int x = ((unsigned int)u) << 16;
  return __builtin_bit_cast(float, x);
}
__device__ __forceinline__ unsigned short f2u(float f) {
  unsigned int x = __builtin_bit_cast(unsigned int, f);
  x += 0x7FFFu + ((x >> 16) & 1u);   // RNE
  return (unsigned short)(x >> 16);
}
__device__ __forceinline__ unsigned int cvt_pk_bf16(float lo, float hi) {
  unsigned int r;
  asm("v_cvt_pk_bf16_f32 %0, %1, %2" : "=v"(r) : "v"(lo), "v"(hi));
  return r;
}

#define QSCALE 0.36067376022224085f   // 0.25 * log2(e)

// ws layout (bytes). Aliases safe per kernel ordering.
#define O_XHT 0ull                      // f32 residual 1 [16384][128]  8MB
#define O_H1  (8ull << 20)              // bf16 LN1 out   [16384][128]  4MB
#define O_QB  (12ull << 20)             // bf16 Q (pre-scaled)          4MB
#define O_XH1 (16ull << 20)             // f32 residual 2 [16384][128]  8MB
#define O_KP  (24ull << 20)             // bf16 K padded  [144*144][128]
#define O_VP  (O_KP + 5308416ull)       // bf16 V padded  [144*144][128]
#define O_VPT (O_VP + 5308416ull)       // bf16 V^T       [128][144*144]
#define O_M1  O_KP                      // bf16 MLP mid   [16384][512] 16MB
#define O_WB  (O_KP + (16ull << 20))    // bf16 weights   ~384KB
#define PADT  20736                     // 144*144 padded tokens

// ---------------- all weights f32 -> bf16 in one launch --------------------
__global__ __launch_bounds__(256) void cvtall_kernel(
    const float* __restrict__ a, const float* __restrict__ b,
    const float* __restrict__ c, const float* __restrict__ d,
    unsigned short* __restrict__ dst) {
  const int i = (blockIdx.x * 256 + threadIdx.x) * 4;
  const float* s; int lo;
  if (i < 49152)       { s = a; lo = 0; }
  else if (i < 65536)  { s = b; lo = 49152; }
  else if (i < 131072) { s = c; lo = 65536; }
  else                 { s = d; lo = 131072; }
  const float4 v = *(const float4*)(s + (i - lo));
  ushort4 o;
  o.x = f2u(v.x); o.y = f2u(v.y); o.z = f2u(v.z); o.w = f2u(v.w);
  *(ushort4*)(dst + i) = o;
}

// ------------- zero only the halo pad rows/cols of kp and vp ---------------
__global__ __launch_bounds__(256) void padzero_kernel(
    unsigned short* __restrict__ kp, unsigned short* __restrict__ vp) {
  const int idx = blockIdx.x * 256 + threadIdx.x;
  if (idx >= 4352) return;
  int r, c;
  if (idx < 2304) {               // top 8 + bottom 8 full rows (16 x 144)
    const int rr = idx / 144;
    r = (rr < 8) ? rr : rr + 128;
    c = idx - rr * 144;
  } else {                        // side cols of rows 8..135 (128 x 16)
    const int i2 = idx - 2304;
    r = 8 + (i2 >> 4);
    const int cc = i2 & 15;
    c = (cc < 8) ? cc : cc + 128;
  }
  const size_t off = ((size_t)r * 144 + c) * 128;
  const u32x4 z = {};
#pragma unroll
  for (int k = 0; k < 16; k++) {
    *(u32x4*)(kp + off + k * 8) = z;
    *(u32x4*)(vp + off + k * 8) = z;
  }
}

// ------------- LN1 + NCHW->NHWC via LDS transpose tile ---------------------
__global__ __launch_bounds__(256) void ln1_kernel(
    const float* __restrict__ x,
    const float* __restrict__ lw, const float* __restrict__ lb,
    float* __restrict__ xh_t, unsigned short* __restrict__ h1) {
  __shared__ float ld[128][33];
  const int t0 = blockIdx.x * 32;
  const int tid = threadIdx.x;
  {
    const int c = tid >> 1, th = (tid & 1) * 16;
    const float* src = x + (size_t)c * 16384 + t0 + th;
#pragma unroll
    for (int i = 0; i < 4; i++) {
      const float4 v = *(const float4*)(src + i * 4);
      ld[c][th + i * 4]     = v.x;
      ld[c][th + i * 4 + 1] = v.y;
      ld[c][th + i * 4 + 2] = v.z;
      ld[c][th + i * 4 + 3] = v.w;
    }
  }
  __syncthreads();
  const int t = tid >> 3, cp = (tid & 7) * 16;
  float vals[16];
  float s = 0.f, q = 0.f;
#pragma unroll
  for (int i = 0; i < 16; i++) {
    const float v = ld[cp + i][t];
    vals[i] = v;
    s += v; q += v * v;
  }
  s += __shfl_xor(s, 1); q += __shfl_xor(q, 1);
  s += __shfl_xor(s, 2); q += __shfl_xor(q, 2);
  s += __shfl_xor(s, 4); q += __shfl_xor(q, 4);
  const float mu = s * 0.0078125f;
  const float rs = rsqrtf(q * 0.0078125f - mu * mu + 1e-5f);
  float* xrow = xh_t + (size_t)(t0 + t) * 128 + cp;
#pragma unroll
  for (int i = 0; i < 4; i++)
    *(float4*)(xrow + i * 4) =
        float4{vals[4*i], vals[4*i+1], vals[4*i+2], vals[4*i+3]};
  unsigned int pk[8];
#pragma unroll
  for (int k = 0; k < 8; k++) {
    const float y0 = (vals[2*k]   - mu) * rs * lw[cp + 2*k]   + lb[cp + 2*k];
    const float y1 = (vals[2*k+1] - mu) * rs * lw[cp + 2*k+1] + lb[cp + 2*k+1];
    pk[k] = cvt_pk_bf16(y0, y1);
  }
  unsigned int* hrow = (unsigned int*)(h1 + (size_t)(t0 + t) * 128 + cp);
  *(u32x4*)(hrow)     = u32x4{pk[0], pk[1], pk[2], pk[3]};
  *(u32x4*)(hrow + 4) = u32x4{pk[4], pk[5], pk[6], pk[7]};
}

// ------------------- V transpose: vp[PADT][128] -> vpt[128][PADT] ----------
__global__ __launch_bounds__(256) void vtrans_kernel(
    const unsigned short* __restrict__ vp, unsigned short* __restrict__ vpt) {
  __shared__ unsigned short t[64][130];
  const int r0 = blockIdx.x * 64;
  const int tid = threadIdx.x;
  {
    const int c = tid & 127, rh = tid >> 7;
    for (int it = 0; it < 32; it++) {
      const int r = it * 2 + rh;
      t[r][c] = vp[(size_t)(r0 + r) * 128 + c];
    }
  }
  __syncthreads();
  {
    const int r = tid & 63, ch = tid >> 6;
    for (int it = 0; it < 32; it++) {
      const int col = it * 4 + ch;
      vpt[(size_t)col * PADT + r0 + r] = t[r][col];
    }
  }
}

// ------------------------------ generic GEMM -------------------------------
enum { EPI_QKV = 0, EPI_GELU = 2, EPI_FC2 = 3 };

template <int EPI, int K>
__global__ __launch_bounds__(256) void gemm_kernel(
    const unsigned short* __restrict__ A,
    const unsigned short* __restrict__ B,
    const float* __restrict__ bias,
    void* __restrict__ o0, void* __restrict__ o1, void* __restrict__ o2,
    const void* __restrict__ aux) {
  const int tid = threadIdx.x;
  const int w = tid >> 6, l = tid & 63;
  const int lr = l & 15, lg = l >> 4;
  const int mB = blockIdx.x * 64, nB = blockIdx.y * 64;
  const int ml = (w >> 1) * 32, nl2 = (w & 1) * 32;
  const int m0 = mB + ml, n0 = nB + nl2;
  f32x4 acc[2][2] = {};
  const unsigned short* Ar0 = A + (size_t)(m0 + lr) * K + lg * 8;
  const unsigned short* Ar1 = Ar0 + 16 * K;
  const unsigned short* Br0 = B + (size_t)(n0 + lr) * K + lg * 8;
  const unsigned short* Br1 = Br0 + 16 * K;
  for (int k = 0; k < K; k += 32) {
    bf16x8 a0 = *(const bf16x8*)(Ar0 + k);
    bf16x8 a1 = *(const bf16x8*)(Ar1 + k);
    bf16x8 b0 = *(const bf16x8*)(Br0 + k);
    bf16x8 b1 = *(const bf16x8*)(Br1 + k);
    acc[0][0] = MFMA16(a0, b0, acc[0][0]);
    acc[0][1] = MFMA16(a0, b1, acc[0][1]);
    acc[1][0] = MFMA16(a1, b0, acc[1][0]);
    acc[1][1] = MFMA16(a1, b1, acc[1][1]);
  }

  if constexpr (EPI == EPI_FC2) {
    __shared__ float tb[64][65];
#pragma unroll
    for (int j = 0; j < 2; j++) {
      const int jl = nl2 + j * 16 + lr;
      const float bv = bias[nB + jl];
#pragma unroll
      for (int i = 0; i < 2; i++)
#pragma unroll
        for (int r = 0; r < 4; r++) {
          const int il = ml + i * 16 + lg * 4 + r;
          tb[jl][il] = acc[i][j][r] + bv +
                       ((const float*)aux)[(size_t)(mB + il) * 128 + (nB + jl)];
        }
    }
    __syncthreads();
    const int nrow = tid >> 2, mc = (tid & 3) * 16;
    float* op = (float*)o0 + (size_t)(nB + nrow) * 16384 + mB + mc;
#pragma unroll
    for (int kk = 0; kk < 4; kk++)
      *(float4*)(op + kk * 4) = *(const float4*)&tb[nrow][mc + kk * 4];
  } else {
#pragma unroll
    for (int j = 0; j < 2; j++) {
      const int jj = n0 + j * 16 + lr;
      const float bv = bias[jj];
#pragma unroll
      for (int i = 0; i < 2; i++) {
#pragma unroll
        for (int r = 0; r < 4; r++) {
          const int ii = m0 + i * 16 + lg * 4 + r;
          float v = acc[i][j][r] + bv;
          if constexpr (EPI == EPI_QKV) {
            const int gh = ii >> 7, gw = ii & 127;
            const size_t prow = (size_t)(gh + 8) * 144 + (gw + 8);
            if (jj < 128)
              ((unsigned short*)o0)[(size_t)ii * 128 + jj] = f2u(v * QSCALE);
            else if (jj < 256)
              ((unsigned short*)o1)[prow * 128 + (jj - 128)] = f2u(v);
            else
              ((unsigned short*)o2)[prow * 128 + (jj - 256)] = f2u(v);
          } else {  // EPI_GELU: tanh-form GELU, one exp2 + rcp
            const float y = 0.7978845608f * (v + 0.044715f * v * v * v);
            const float E = __builtin_amdgcn_exp2f(y * 2.8853900818f);
            const float g = v - v * __builtin_amdgcn_rcpf(E + 1.0f);
            ((unsigned short*)o0)[(size_t)ii * 512 + jj] = f2u(g);
          }
        }
      }
    }
  }
}

// ---------------- proj GEMM + residual + LN2 (fused) -----------------------
__global__ __launch_bounds__(256) void projln2_kernel(
    const unsigned short* __restrict__ A,    // attnb
    const unsigned short* __restrict__ B,    // proj_wb
    const float* __restrict__ bias,
    const float* __restrict__ xh_t,
    const float* __restrict__ lw, const float* __restrict__ lb,
    float* __restrict__ xh1, unsigned short* __restrict__ h2) {
  __shared__ float sred[2][64][2];
  const int tid = threadIdx.x;
  const int w = tid >> 6, l = tid & 63;
  const int lr = l & 15, lg = l >> 4;
  const int mh = w >> 1, nh = w & 1;
  const int mB = blockIdx.x * 64;
  const int m0 = mB + mh * 32, n0 = nh * 64;
  f32x4 acc[2][4] = {};
  const unsigned short* Ar0 = A + (size_t)(m0 + lr) * 128 + lg * 8;
  const unsigned short* Ar1 = Ar0 + 16 * 128;
  const unsigned short* Br = B + (size_t)(n0 + lr) * 128 + lg * 8;
  for (int k = 0; k < 128; k += 32) {
    const bf16x8 a0 = *(const bf16x8*)(Ar0 + k);
    const bf16x8 a1 = *(const bf16x8*)(Ar1 + k);
#pragma unroll
    for (int j = 0; j < 4; j++) {
      const bf16x8 bj = *(const bf16x8*)(Br + (size_t)j * 16 * 128 + k);
      acc[0][j] = MFMA16(a0, bj, acc[0][j]);
      acc[1][j] = MFMA16(a1, bj, acc[1][j]);
    }
  }
  float vv[2][4][4];   // [i][r][j]
#pragma unroll
  for (int j = 0; j < 4; j++) {
    const int jj = n0 + j * 16 + lr;
    const float bv = bias[jj];
#pragma unroll
    for (int i = 0; i < 2; i++)
#pragma unroll
      for (int r = 0; r < 4; r++) {
        const int ii = mB + mh * 32 + i * 16 + lg * 4 + r;
        const float v = acc[i][j][r] + bv + xh_t[(size_t)ii * 128 + jj];
        xh1[(size_t)ii * 128 + jj] = v;
        vv[i][r][j] = v;
      }
  }
#pragma unroll
  for (int i = 0; i < 2; i++)
#pragma unroll
    for (int r = 0; r < 4; r++) {
      float s = vv[i][r][0] + vv[i][r][1] + vv[i][r][2] + vv[i][r][3];
      float q = vv[i][r][0] * vv[i][r][0] + vv[i][r][1] * vv[i][r][1] +
                vv[i][r][2] * vv[i][r][2] + vv[i][r][3] * vv[i][r][3];
      s += __shfl_xor(s, 1); q += __shfl_xor(q, 1);
      s += __shfl_xor(s, 2); q += __shfl_xor(q, 2);
      s += __shfl_xor(s, 4); q += __shfl_xor(q, 4);
      s += __shfl_xor(s, 8); q += __shfl_xor(q, 8);
      if (lr == 0) {
        const int tl = mh * 32 + i * 16 + lg * 4 + r;
        sred[nh][tl][0] = s;
        sred[nh][tl][1] = q;
      }
    }
  __syncthreads();
#pragma unroll
  for (int i = 0; i < 2; i++)
#pragma unroll
    for (int r = 0; r < 4; r++) {
      const int tl = mh * 32 + i * 16 + lg * 4 + r;
      const float s = sred[0][tl][0] + sred[1][tl][0];
      const float q = sred[0][tl][1] + sred[1][tl][1];
      const float mu = s * 0.0078125f;
      const float rs = rsqrtf(q * 0.0078125f - mu * mu + 1e-5f);
#pragma unroll
      for (int j = 0; j < 4; j++) {
        const int jj = n0 + j * 16 + lr;
        const float y = (vv[i][r][j] - mu) * rs * lw[jj] + lb[jj];
        h2[(size_t)(mB + tl) * 128 + jj] = f2u(y);
      }
    }
}

// ------------------------------ halo attention -----------------------------
// Block = (win, head, qhalf), win = bid&63. 4 waves x 32 queries (2 q-tiles).
// QK^T: validated 16x16x32 path (kf0/kf1 keys, lg<2 predication on K-frag).
// P staging: lane (lr,lg) holds pk[r] = (P[key=lg*4+r][q=lr], P[key+16][q=lr])
// packed as u32 -> ONE ds_write_b128 into tile[q=lr][slot=lg*4+r]; the PV
// A-frag (q=lr, keys lg*8..+7) reads back as 2x ds_read_b128 + 4x v_perm
// (slot s holds keys (s, s+16); lg<2 takes lo halves, lg>=2 hi halves).
// Denominator: den = mfma(pa, ones) -- register-aligned with numerator.
// Q pre-scaled by 0.25*log2(e): p = exp2(s) = exp(qk/4); zero-padded OOB
// keys give exp2(0)=1 terms, matching reference softmax exactly.
__global__ __launch_bounds__(256) void attn_kernel(
    const unsigned short* __restrict__ qb,
    const unsigned short* __restrict__ kp,
    const unsigned short* __restrict__ vpt,
    unsigned short* __restrict__ attnb) {
  __shared__ unsigned int pl[4][16][20];   // per-wave [q][slot], 80B rows
  const int bid = blockIdx.x;
  const int win = bid & 63;
  const int sub = bid >> 6;
  const int qh = sub & 1, head = sub >> 1;
  const int wy = win >> 3, wx = win & 7;
  const int tid = threadIdx.x;
  const int wv = tid >> 6, l = tid & 63;
  const int lr = l & 15, lg = l >> 4;

  // Q^T B-frags: col q = lr, k = hd = lg*8+e (real only k<16)
  bf16x8 qf[2];
#pragma unroll
  for (int qt = 0; qt < 2; qt++) {
    bf16x8 t = {};
    if (lg < 2) {
      const int qi = qh * 128 + wv * 32 + qt * 16 + lr;
      const int gh = wy * 16 + (qi >> 4), gw = wx * 16 + (qi & 15);
      t = *(const bf16x8*)(qb + ((size_t)(gh * 128 + gw)) * 128 + head * 16 + lg * 8);
    }
    qf[qt] = t;
  }

  bf16x8 ones;
#pragma unroll
  for (int e = 0; e < 8; e++) ones[e] = (short)0x3F80;   // bf16 1.0

  f32x4 acc[2] = {}, den[2] = {};
  unsigned int* wp = &pl[wv][lr][lg * 4];
  const unsigned int* rp = &pl[wv][lr][(lg & 1) * 8];
  const unsigned int psel = (lg >= 2) ? 0x07060302u : 0x05040100u;

  const unsigned short* kbase =
      kp + ((size_t)(wy * 16) * 144 + wx * 16 + lr) * 128 + head * 16 + lg * 8;
  const unsigned short* vbase =
      vpt + (size_t)(head * 16 + lr) * PADT + (size_t)(wy * 16) * 144 + wx * 16 + lg * 8;

  for (int kr = 0; kr < 32; kr++) {
    bf16x8 kf0 = {}, kf1 = {};
    if (lg < 2) {
      const unsigned short* kr0 = kbase + (size_t)kr * 144 * 128;
      kf0 = *(const bf16x8*)(kr0);
      kf1 = *(const bf16x8*)(kr0 + 16 * 128);
    }
    const bf16x8 vf = *(const bf16x8*)(vbase + kr * 144);
#pragma unroll
    for (int qt = 0; qt < 2; qt++) {
      f32x4 s0 = {}, s1 = {};
      s0 = MFMA16(kf0, qf[qt], s0);   // P[key=lg*4+r][q=lr]
      s1 = MFMA16(kf1, qf[qt], s1);   // P[key=16+lg*4+r][q=lr]
      unsigned int pk[4];
#pragma unroll
      for (int r = 0; r < 4; r++)
        pk[r] = cvt_pk_bf16(__builtin_amdgcn_exp2f(s0[r]),
                            __builtin_amdgcn_exp2f(s1[r]));
      *(u32x4*)wp = u32x4{pk[0], pk[1], pk[2], pk[3]};
      const u32x4 in0 = *(const u32x4*)(rp);
      const u32x4 in1 = *(const u32x4*)(rp + 4);
      u32x4 pa;
      pa[0] = __builtin_amdgcn_perm(in0[1], in0[0], psel);
      pa[1] = __builtin_amdgcn_perm(in0[3], in0[2], psel);
      pa[2] = __builtin_amdgcn_perm(in1[1], in1[0], psel);
      pa[3] = __builtin_amdgcn_perm(in1[3], in1[2], psel);
      const bf16x8 paf = __builtin_bit_cast(bf16x8, pa);
      acc[qt] = MFMA16(paf, vf, acc[qt]);
      den[qt] = MFMA16(paf, ones, den[qt]);
    }
  }

#pragma unroll
  for (int qt = 0; qt < 2; qt++)
#pragma unroll
    for (int r = 0; r < 4; r++) {
      const int q0 = qt * 16 + lg * 4 + r;
      const int qi2 = qh * 128 + wv * 32 + q0;
      const int gh2 = wy * 16 + (qi2 >> 4), gw2 = wx * 16 + (qi2 & 15);
      attnb[((size_t)(gh2 * 128 + gw2)) * 128 + head * 16 + lr] =
          f2u(acc[qt][r] * __builtin_amdgcn_rcpf(den[qt][r]));
    }
}

// ------------------------------- launcher ----------------------------------
extern "C" void kernel_launch(void* const* d_in, const int* in_sizes, int n_in,
                              void* d_out, int out_size, void* d_ws, size_t ws_size,
                              hipStream_t stream) {
  const float* x      = (const float*)d_in[0];
  const float* ln1w   = (const float*)d_in[1];
  const float* ln1b   = (const float*)d_in[2];
  const float* qkv_w  = (const float*)d_in[3];
  const float* qkv_b  = (const float*)d_in[4];
  const float* proj_w = (const float*)d_in[5];
  const float* proj_b = (const float*)d_in[6];
  const float* ln2w   = (const float*)d_in[7];
  const float* ln2b   = (const float*)d_in[8];
  const float* fc1_w  = (const float*)d_in[9];
  const float* fc1_b  = (const float*)d_in[10];
  const float* fc2_w  = (const float*)d_in[11];
  const float* fc2_b  = (const float*)d_in[12];

  char* ws = (char*)d_ws;
  float*          xh_t = (float*)(ws + O_XHT);
  unsigned short* h1   = (unsigned short*)(ws + O_H1);
  unsigned short* qb   = (unsigned short*)(ws + O_QB);
  float*          xh1  = (float*)(ws + O_XH1);
  unsigned short* kp   = (unsigned short*)(ws + O_KP);
  unsigned short* vp   = (unsigned short*)(ws + O_VP);
  unsigned short* vpt  = (unsigned short*)(ws + O_VPT);
  unsigned short* m1   = (unsigned short*)(ws + O_M1);
  unsigned short* wb   = (unsigned short*)(ws + O_WB);
  unsigned short* attnb = h1;   // h1 dead after QKV GEMM consumed it
  unsigned short* h2    = qb;   // qb dead after attention
  float* outp = (float*)d_out;

  unsigned short* qkv_wb  = wb;            // 49152
  unsigned short* proj_wb = wb + 49152;    // 16384
  unsigned short* fc1_wb  = wb + 65536;    // 65536
  unsigned short* fc2_wb  = wb + 131072;   // 65536

  cvtall_kernel<<<192, 256, 0, stream>>>(qkv_w, proj_w, fc1_w, fc2_w, wb);
  padzero_kernel<<<17, 256, 0, stream>>>(kp, vp);

  ln1_kernel<<<512, 256, 0, stream>>>(x, ln1w, ln1b, xh_t, h1);
  gemm_kernel<EPI_QKV, 128><<<dim3(256, 6), 256, 0, stream>>>(
      h1, qkv_wb, qkv_b, qb, kp, vp, nullptr);
  vtrans_kernel<<<324, 256, 0, stream>>>(vp, vpt);
  attn_kernel<<<1024, 256, 0, stream>>>(qb, kp, vpt, attnb);
  projln2_kernel<<<256, 256, 0, stream>>>(
      attnb, proj_wb, proj_b, xh_t, ln2w, ln2b, xh1, h2);
  gemm_kernel<EPI_GELU, 128><<<dim3(256, 8), 256, 0, stream>>>(
      h2, fc1_wb, fc1_b, m1, nullptr, nullptr, nullptr);
  gemm_kernel<EPI_FC2, 512><<<dim3(256, 2), 256, 0, stream>>>(
      m1, fc2_wb, fc2_b, outp, nullptr, nullptr, xh1);
}